// Round 15
// baseline (251.109 us; speedup 1.0000x reference)
//
#include <hip/hip_runtime.h>
#include <hip/hip_bf16.h>
#include <stdint.h>
#include <stddef.h>

// Problem constants (MultiHeadAttention_52759378264454)
constexpr int T_SEQ = 1024;
constexpr int BATCH = 8;
constexpr int DIN   = 256;
constexpr int NH    = 8;
constexpr int EH    = 512;
constexpr int HE    = NH * EH;        // 4096
constexpr int BT    = BATCH * T_SEQ;  // 8192
constexpr float SCALE = 0.044194173824159216f; // 1/sqrt(512)
constexpr float C2   = 0.06375814170236324f;   // SCALE * log2(e)

typedef __attribute__((ext_vector_type(8)))  short s16x8;
typedef __attribute__((ext_vector_type(4)))  short s16x4;
typedef __attribute__((ext_vector_type(16))) float f32x16;

__device__ __forceinline__ short f2bf(float f) {
  __hip_bfloat16 h = __float2bfloat16(f);   // RNE; compiler can pack cvt_pk
  union { __hip_bfloat16 h; short s; } c; c.h = h;
  return c.s;
}
__device__ __forceinline__ float bf2f(short s) {
  union { uint32_t u; float f; } c; c.u = ((uint32_t)(uint16_t)s) << 16;
  return c.f;
}

// async global->LDS, 16B/lane. LDS dest = wave-uniform base + lane*16 (HW).
__device__ __forceinline__ void gload16(const short* g, short* l) {
  __builtin_amdgcn_global_load_lds(
      (__attribute__((address_space(1))) void*)(void*)const_cast<short*>(g),
      (__attribute__((address_space(3))) void*)(void*)l, 16, 0, 0);
}

#define WAITVM(N) asm volatile("s_waitcnt vmcnt(" #N ")" ::: "memory")
#define BARF do { asm volatile("" ::: "memory"); __builtin_amdgcn_s_barrier(); \
                  asm volatile("" ::: "memory"); } while (0)

// ---------------------------------------------------------------------------
// r5 core (best measured): 8-wave 256x128 GEMM, BK=32, mfma_f32_32x32x16_bf16,
// double-buffered 48 KiB LDS, counted vmcnt(3) (tile t+2 in flight).
// C[256,128] += A[256,K]*B[128,K]^T, K-major bf16. Waves 4wm x 2wn, 64x64 ea.
// Trailing barrier at loop end (safe to reuse LDS / call again).
// ---------------------------------------------------------------------------
template<int NT>   // K = NT*32, NT >= 2
__device__ __forceinline__ void gemm32(const short* __restrict__ Ag, int lda,
                                       const short* __restrict__ Bg, int ldb,
                                       short* lds, f32x16 (&acc)[2][2])
{
  const int tid = threadIdx.x;
  const int l   = tid & 63, wv = tid >> 6;
  const int hi  = l >> 5;
  const int Rw  = (wv >> 1) * 64, Cw = (wv & 1) * 64;
  const int fl  = (l & 3) ^ ((l >> 2) & 3);

  int oA[2][2], oB[2][2];
#pragma unroll
  for (int kk = 0; kk < 2; ++kk) {
    int cp = (((kk << 1) | hi) ^ fl) * 8;
#pragma unroll
    for (int mi = 0; mi < 2; ++mi) oA[kk][mi] = (Rw + mi * 32 + (l & 31)) * 32 + cp;
#pragma unroll
    for (int ni = 0; ni < 2; ++ni) oB[kk][ni] = 8192 + (Cw + ni * 32 + (l & 31)) * 32 + cp;
  }

  const int rA0 = tid >> 2;
  const int sA0 = ((tid & 3) ^ ((rA0 & 3) ^ ((rA0 >> 2) & 3))) * 8;
  const int cA1 = tid + 512, rA1 = cA1 >> 2;
  const int sA1 = ((cA1 & 3) ^ ((rA1 & 3) ^ ((rA1 >> 2) & 3))) * 8;
  const int dA0 = (wv * 64) * 8, dA1 = (wv * 64 + 512) * 8, dB0 = 8192 + (wv * 64) * 8;

  auto stage = [&](int t) {
    short* slot = lds + (t & 1) * 12288;
    const int ko = t * 32;
    gload16(Ag + (size_t)rA0 * lda + ko + sA0, slot + dA0);
    gload16(Ag + (size_t)rA1 * lda + ko + sA1, slot + dA1);
    gload16(Bg + (size_t)rA0 * ldb + ko + sA0, slot + dB0);
  };

  stage(0); stage(1);

#pragma unroll 1
  for (int t = 0; t < NT; ++t) {
    const short* buf = lds + (t & 1) * 12288;
    if (t == NT - 1) { WAITVM(0); } else { WAITVM(3); }
    BARF;
#pragma unroll
    for (int kk = 0; kk < 2; ++kk) {
      s16x8 a0 = *(const s16x8*)(buf + oA[kk][0]);
      s16x8 a1 = *(const s16x8*)(buf + oA[kk][1]);
      s16x8 b0 = *(const s16x8*)(buf + oB[kk][0]);
      s16x8 b1 = *(const s16x8*)(buf + oB[kk][1]);
      __builtin_amdgcn_s_setprio(1);
      acc[0][0] = __builtin_amdgcn_mfma_f32_32x32x16_bf16(a0, b0, acc[0][0], 0, 0, 0);
      acc[0][1] = __builtin_amdgcn_mfma_f32_32x32x16_bf16(a0, b1, acc[0][1], 0, 0, 0);
      acc[1][0] = __builtin_amdgcn_mfma_f32_32x32x16_bf16(a1, b0, acc[1][0], 0, 0, 0);
      acc[1][1] = __builtin_amdgcn_mfma_f32_32x32x16_bf16(a1, b1, acc[1][1], 0, 0, 0);
      __builtin_amdgcn_s_setprio(0);
    }
    BARF;
    if (t + 2 < NT) stage(t + 2);
  }
}

#define CROW(mi, reg) ((wv >> 1) * 64 + (mi) * 32 + ((reg) & 3) + 8 * ((reg) >> 2) + 4 * hi)
#define CCOL(ni)      ((wv & 1) * 64 + (ni) * 32 + (l & 31))

// ---------------------------------------------------------------------------
// K0: fused fp32->bf16 cast; Qb transposed to [b][t][d]; weights copied.
// ---------------------------------------------------------------------------
__global__ __launch_bounds__(256) void k_cvt_all(
    const float* __restrict__ Q,  const float* __restrict__ Wq,
    const float* __restrict__ Wk, const float* __restrict__ Wv,
    const float* __restrict__ Wo, short* __restrict__ dst)
{
  constexpr int N_Q = 524288;              // 1024*8*256/4
  constexpr int N_W = 262144;              // 8*512*256/4
  constexpr int TOT = N_Q + 4 * N_W;
  int i  = blockIdx.x * 256 + threadIdx.x;
  int st = gridDim.x * 256;
  for (; i < TOT; i += st) {
    const float* s; int off;
    if (i < N_Q) {
      int b = i >> 16, t = (i >> 6) & 1023, d4 = i & 63;
      s = Q; off = (t * 8 + b) * 64 + d4;
    }
    else if (i < N_Q + N_W)     { s = Wq; off = i - N_Q; }
    else if (i < N_Q + 2 * N_W) { s = Wk; off = i - N_Q - N_W; }
    else if (i < N_Q + 3 * N_W) { s = Wv; off = i - N_Q - 2 * N_W; }
    else                        { s = Wo; off = i - N_Q - 3 * N_W; }
    float4 v = ((const float4*)s)[off];
    s16x4 o = { f2bf(v.x), f2bf(v.y), f2bf(v.z), f2bf(v.w) };
    ((s16x4*)dst)[i] = o;
  }
}

// ---------------------------------------------------------------------------
// K_wtr: WT[mat][h][d][e] = W[mat][h][e][d]  (mat 0..2 = Wq,Wk,Wv)
// grid (4 d-tiles, 8 e-tiles, 24 = mat*8+h), 256 thr
// ---------------------------------------------------------------------------
__global__ __launch_bounds__(256) void k_wtr(const short* __restrict__ Wbase,
                                             short* __restrict__ WT)
{
  __shared__ short tl[64][72];
  const int dt = blockIdx.x, et = blockIdx.y, mz = blockIdx.z;
  const int mat = mz >> 3, h = mz & 7;
  const short* src = Wbase + ((size_t)mat * NH + h) * EH * DIN;
  short* dst = WT + ((size_t)mat * NH + h) * DIN * EH;
  const int tid = threadIdx.x;

#pragma unroll
  for (int rep = 0; rep < 2; ++rep) {
    int er = (tid >> 3) + rep * 32;
    int dc = (tid & 7) * 8;
    s16x8 v = *(const s16x8*)&src[(size_t)(et * 64 + er) * DIN + dt * 64 + dc];
#pragma unroll
    for (int j = 0; j < 8; ++j) tl[er][dc + j] = v[j];
  }
  __syncthreads();
#pragma unroll
  for (int rep = 0; rep < 2; ++rep) {
    int dr = (tid >> 3) + rep * 32;
    int ec = (tid & 7) * 8;
    s16x8 o;
#pragma unroll
    for (int j = 0; j < 8; ++j) o[j] = tl[ec + j][dr];
    *(s16x8*)&dst[(size_t)(dt * 64 + dr) * EH + et * 64 + ec] = o;
  }
}

// ---------------------------------------------------------------------------
// K_prep: p=0: GT[h][d2][d1] = sum_e WkT[h][d2,e]*WqT[h][d1,e]  (= Wq^T Wk)
//         p=1: Mh[h][d][dd]  = sum_e Wo[d,h*512+e]*WvT[h][dd,e] (= Wo_h Wv_h)
// grid 32: f -> by(1b), h(3b), p(1b).
// ---------------------------------------------------------------------------
__global__ __launch_bounds__(512) void k_prep(
    const short* __restrict__ WT, const short* __restrict__ Wob,
    short* __restrict__ GT, short* __restrict__ Mh)
{
  __shared__ short lds[24576];
  const int f = blockIdx.x;
  const int by = f & 1, h = (f >> 1) & 7, p = f >> 4;

  const short* WqT = WT + (size_t)0 * NH * DIN * EH + (size_t)h * DIN * EH;
  const short* WkT = WT + (size_t)1 * NH * DIN * EH + (size_t)h * DIN * EH;
  const short* WvT = WT + (size_t)2 * NH * DIN * EH + (size_t)h * DIN * EH;

  const short* Ag; int lda; const short* Bg; int ldb; short* Cg;
  if (p == 0) { Ag = WkT; lda = EH; Bg = WqT + (size_t)by * 128 * EH; ldb = EH;
                Cg = GT + (size_t)h * 65536; }
  else        { Ag = Wob + (size_t)h * EH; lda = HE;
                Bg = WvT + (size_t)by * 128 * EH; ldb = EH;
                Cg = Mh + (size_t)h * 65536; }

  f32x16 acc[2][2] = {};
  gemm32<EH / 32>(Ag, lda, Bg, ldb, lds, acc);

  const int l = threadIdx.x & 63, wv = threadIdx.x >> 6, hi = l >> 5;
#pragma unroll
  for (int ni = 0; ni < 2; ++ni) {
    int col = by * 128 + CCOL(ni);
#pragma unroll
    for (int mi = 0; mi < 2; ++mi)
#pragma unroll
      for (int reg = 0; reg < 16; ++reg)
        Cg[(size_t)CROW(mi, reg) * 256 + col] = f2bf(acc[mi][ni][reg]);
  }
}

// ---------------------------------------------------------------------------
// K_vec (parallel): grid 25 x 256 thr. blocks 0..23: (mat, h), thread = d.
// block 24: c0[h] = sum_e bq*bk.
// ---------------------------------------------------------------------------
__global__ __launch_bounds__(256) void k_vec(
    const short* __restrict__ WT, const short* __restrict__ Wob,
    const float* __restrict__ bq, const float* __restrict__ bk,
    const float* __restrict__ bv,
    float* __restrict__ uA, float* __restrict__ wA,
    float* __restrict__ wbA, float* __restrict__ c0A)
{
  const int f = blockIdx.x;
  const int d = threadIdx.x;
  if (f < 24) {
    const int mat = f >> 3, h = f & 7;
    __shared__ float bL[512];
    const float* bias = (mat == 0 ? bk : mat == 1 ? bq : bv) + h * EH;
    bL[d] = bias[d];
    bL[d + 256] = bias[d + 256];
    __syncthreads();
    const short* row;
    if (mat == 0)      row = WT + ((size_t)h * DIN + d) * EH;               // WqT
    else if (mat == 1) row = WT + ((size_t)(NH + h) * DIN + d) * EH;        // WkT
    else               row = Wob + (size_t)d * HE + h * EH;                 // Wo
    float acc = 0.f;
#pragma unroll 4
    for (int e8 = 0; e8 < EH; e8 += 8) {
      s16x8 v = *(const s16x8*)(row + e8);
#pragma unroll
      for (int j = 0; j < 8; ++j) acc += bf2f(v[j]) * bL[e8 + j];
    }
    float* out = (mat == 0 ? uA : mat == 1 ? wA : wbA);
    out[h * 256 + d] = acc;
  } else {
    const int h = d >> 5, i = d & 31;
    float c = 0.f;
#pragma unroll
    for (int j = 0; j < 16; ++j) {
      int e = i * 16 + j;
      c += bq[h * EH + e] * bk[h * EH + e];
    }
    c += __shfl_xor(c, 1);  c += __shfl_xor(c, 2);
    c += __shfl_xor(c, 4);  c += __shfl_xor(c, 8);
    c += __shfl_xor(c, 16);
    if (i == 0) c0A[h] = c;
  }
}

// ---------------------------------------------------------------------------
// K_qg: qg[h][m][d2] = sum_d1 Qb[m,d1]*GT[h][d2,d1].  grid (32,2,8). NT=8.
// ---------------------------------------------------------------------------
__global__ __launch_bounds__(512) void k_qg(
    const short* __restrict__ Qb, const short* __restrict__ GT,
    short* __restrict__ qg)
{
  __shared__ short lds[24576];
  const int bx = blockIdx.x, by = blockIdx.y, h = blockIdx.z;
  const short* Ag = Qb + (size_t)bx * 256 * DIN;
  const short* Bg = GT + (size_t)h * 65536 + (size_t)by * 128 * 256;

  f32x16 acc[2][2] = {};
  gemm32<DIN / 32>(Ag, DIN, Bg, 256, lds, acc);

  short* outp = qg + (size_t)h * BT * 256;
  const int l = threadIdx.x & 63, wv = threadIdx.x >> 6, hi = l >> 5;
#pragma unroll
  for (int ni = 0; ni < 2; ++ni) {
    int col = by * 128 + CCOL(ni);
#pragma unroll
    for (int mi = 0; mi < 2; ++mi)
#pragma unroll
      for (int reg = 0; reg < 16; ++reg)
        outp[(size_t)(bx * 256 + CROW(mi, reg)) * 256 + col] = f2bf(acc[mi][ni][reg]);
  }
}

// ---------------------------------------------------------------------------
// K_vwg: vwgT[h][d][m] = sum_dd Mh[h][d,dd]*Qb[m,dd] + wb[h][d].
// grid (64 by, 8 h). NT=8.
// ---------------------------------------------------------------------------
__global__ __launch_bounds__(512) void k_vwg(
    const short* __restrict__ Qb, const short* __restrict__ Mh,
    const float* __restrict__ wbA, short* __restrict__ vwgT)
{
  __shared__ short lds[24576];
  const int by = blockIdx.x, h = blockIdx.y;
  const short* Ag = Mh + (size_t)h * 65536;
  const short* Bg = Qb + (size_t)by * 128 * DIN;

  f32x16 acc[2][2] = {};
  gemm32<DIN / 32>(Ag, 256, Bg, DIN, lds, acc);

  short* outp = vwgT + (size_t)h * 256 * BT;
  const int l = threadIdx.x & 63, wv = threadIdx.x >> 6, hi = l >> 5;
#pragma unroll
  for (int mi = 0; mi < 2; ++mi)
#pragma unroll
    for (int reg = 0; reg < 16; ++reg) {
      int d = CROW(mi, reg);
      float bia = wbA[h * 256 + d];
#pragma unroll
      for (int ni = 0; ni < 2; ++ni)
        outp[(size_t)d * BT + by * 128 + CCOL(ni)] = f2bf(acc[mi][ni][reg] + bia);
    }
}

// ---------------------------------------------------------------------------
// K_rc: rt[h][m] = sum_d Qb[m,d]*u[h][d]; ct[h][m] = sum_d Qb[m,d]*w[h][d]
// grid (32), 256 thr.
// ---------------------------------------------------------------------------
__global__ __launch_bounds__(256) void k_rc(
    const short* __restrict__ Qb, const float* __restrict__ uA,
    const float* __restrict__ wA, float* __restrict__ rt, float* __restrict__ ct)
{
  __shared__ float uL[2048], wL[2048];
  const int tid = threadIdx.x;
  for (int i = tid; i < 2048; i += 256) { uL[i] = uA[i]; wL[i] = wA[i]; }
  __syncthreads();
  int m = blockIdx.x * 256 + tid;
  float r[8] = {}, c[8] = {};
  const short* row = Qb + (size_t)m * DIN;
  for (int ch = 0; ch < 32; ++ch) {
    s16x8 v = *(const s16x8*)(row + ch * 8);
#pragma unroll
    for (int j = 0; j < 8; ++j) {
      float q = bf2f(v[j]);
      int d = ch * 8 + j;
#pragma unroll
      for (int h = 0; h < 8; ++h) {
        r[h] += q * uL[h * 256 + d];
        c[h] += q * wL[h * 256 + d];
      }
    }
  }
#pragma unroll
  for (int h = 0; h < 8; ++h) {
    rt[(size_t)h * BT + m] = r[h];
    ct[(size_t)h * BT + m] = c[h];
  }
}

// ---------------------------------------------------------------------------
// K_pgen: P[zz][t][s] = exp2(C2*(qk) + rtL[t] + ctL[s]) + col partials
// rtL/ctL pre-scaled by C2; c0 folded into ctL. grid (4,8,HG*8). K=256, NT=8.
// ---------------------------------------------------------------------------
__global__ __launch_bounds__(512) void k_pgen(
    const short* __restrict__ qg, const short* __restrict__ Qb,
    const float* __restrict__ rt, const float* __restrict__ ct,
    const float* __restrict__ c0A,
    short* __restrict__ Pbuf, float* __restrict__ colpart, int h0, int HG)
{
  __shared__ short lds[24576];
  __shared__ float rtL[256], ctL[128];
  int f = blockIdx.x + (blockIdx.y << 2) + (blockIdx.z << 5);
  int xcd = f & 7, rest = f >> 3;
  int zi = rest % HG, rb = rest / HG;
  int zz = xcd * HG + zi;                       // [0, HG*8)
  int bx = rb & 3, by = rb >> 2;
  const int zg = h0 * 8 + zz;                   // global z
  const int h = zg >> 3, b = zg & 7;

  const short* Ag = qg + ((size_t)h * BT + b * 1024 + bx * 256) * 256;
  const short* Bg = Qb + (size_t)(b * 1024 + by * 128) * 256;

  f32x16 acc[2][2] = {};
  gemm32<DIN / 32>(Ag, 256, Bg, 256, lds, acc);

  const int tid = threadIdx.x;
  const float c0h = c0A[h];
  if (tid < 256)
    rtL[tid] = C2 * rt[(size_t)h * BT + b * 1024 + bx * 256 + tid];
  else if (tid < 384)
    ctL[tid - 256] = C2 * (ct[(size_t)h * BT + b * 1024 + by * 128 + (tid - 256)] + c0h);
  __syncthreads();

  short* Pb = Pbuf + (size_t)zz * T_SEQ * T_SEQ;
  const int l = tid & 63, wv = tid >> 6, hi = l >> 5;

  float cs[2] = {0.f, 0.f};
#pragma unroll
  for (int ni = 0; ni < 2; ++ni) {
    int scol = CCOL(ni);
    float ctv = ctL[scol];
#pragma unroll
    for (int mi = 0; mi < 2; ++mi)
#pragma unroll
      for (int reg = 0; reg < 16; ++reg) {
        int trow = CROW(mi, reg);
        float ev = exp2f(fmaf(acc[mi][ni][reg], C2, rtL[trow] + ctv));
        cs[ni] += ev;
        Pb[(size_t)(bx * 256 + trow) * T_SEQ + by * 128 + scol] = f2bf(ev);
      }
  }
  cs[0] += __shfl_xor(cs[0], 32);
  cs[1] += __shfl_xor(cs[1], 32);
  __syncthreads();
  float* csL = (float*)lds;
  if (l < 32) {
#pragma unroll
    for (int ni = 0; ni < 2; ++ni) csL[(wv >> 1) * 128 + CCOL(ni)] = cs[ni];
  }
  __syncthreads();
  if (tid < 128) {
    float tot = csL[tid] + csL[128 + tid] + csL[256 + tid] + csL[384 + tid];
    colpart[((size_t)zg * 4 + bx) * T_SEQ + by * 128 + tid] = tot;
  }
}

// ---------------------------------------------------------------------------
// K_scalev: vwgT[h][d][b*T+t] *= 1/sum_p colpart[(zg*4+p)][t]
// grid (4 et, HG*8 zz)
// ---------------------------------------------------------------------------
__global__ __launch_bounds__(256) void k_scalev(
    short* __restrict__ vwgT, const float* __restrict__ colpart, int h0, int HG)
{
  __shared__ float invL[1024];
  const int et = blockIdx.x, zz = blockIdx.y;
  const int zg = h0 * 8 + zz;
  const int h = zg >> 3, b = zg & 7;
  const int tid = threadIdx.x;

#pragma unroll
  for (int it = 0; it < 4; ++it) {
    int t = it * 256 + tid;
    float s = 0.f;
#pragma unroll
    for (int p = 0; p < 4; ++p) s += colpart[((size_t)zg * 4 + p) * T_SEQ + t];
    invL[t] = 1.0f / s;
  }
  __syncthreads();

  short* base = vwgT + (size_t)h * 256 * BT + (size_t)et * 64 * BT + (size_t)b * 1024;
  for (int c = tid; c < 64 * 128; c += 256) {
    int row = c >> 7, col = (c & 127) * 8;
    short* p = &base[(size_t)row * BT + col];
    s16x8 v = *(s16x8*)p;
#pragma unroll
    for (int j = 0; j < 8; ++j) v[j] = f2bf(bf2f(v[j]) * invL[col + j]);
    *(s16x8*)p = v;
  }
}

// ---------------------------------------------------------------------------
// K_ogemm (2-head accumulation): for head-pair hp, batch b:
// part[hpg][b*T+t][d] = sum_{h in pair} sum_s P[zz(h,b)][t,s]*vwgT[h][d][b*T+s]
// grid (4 bx, 2 by, (HG/2)*8); same (b,hp) per XCD. fp32 direct store.
// ---------------------------------------------------------------------------
__global__ __launch_bounds__(512) void k_ogemm(
    const short* __restrict__ Pbuf, const short* __restrict__ vwgT,
    float* __restrict__ part, int h0, int HG)
{
  __shared__ short lds[24576];
  const int NP = (HG / 2) * 8;                  // grid.z
  int f = blockIdx.x + (blockIdx.y << 2) + blockIdx.z * 8;
  int xcd = f & 7, rest = f >> 3;
  int pi = rest % (NP / 8 == 0 ? 1 : (NP / 8));  // [0, NP/8)
  int rb = rest / (NP / 8 == 0 ? 1 : (NP / 8));  // [0, 8)
  int zp = xcd * (NP / 8) + pi;                  // [0, NP): b*(HG/2)+hp
  int bx = rb & 3, by = rb >> 2;
  const int b  = zp / (HG / 2);
  const int hp = zp % (HG / 2);
  const int hA = h0 + 2 * hp, hB = hA + 1;
  const int hpg = hA >> 1;                       // global pair index [0,4)

  f32x16 acc[2][2] = {};
#pragma unroll
  for (int u = 0; u < 2; ++u) {
    const int h = u == 0 ? hA : hB;
    const int zz = (h - h0) * 8 + b;             // Pbuf slot
    const short* Ag = Pbuf + (size_t)zz * T_SEQ * T_SEQ + (size_t)bx * 256 * T_SEQ;
    const short* Bg = vwgT + (size_t)h * 256 * BT + (size_t)by * 128 * BT + (size_t)b * 1024;
    gemm32<T_SEQ / 32>(Ag, T_SEQ, Bg, BT, lds, acc);
  }

  float* pp = part + (size_t)hpg * BT * 256;
  const int l = threadIdx.x & 63, wv = threadIdx.x >> 6, hi = l >> 5;
#pragma unroll
  for (int ni = 0; ni < 2; ++ni) {
    int d = by * 128 + CCOL(ni);
#pragma unroll
    for (int mi = 0; mi < 2; ++mi)
#pragma unroll
      for (int reg = 0; reg < 16; ++reg) {
        int m = b * 1024 + bx * 256 + CROW(mi, reg);
        pp[(size_t)m * 256 + d] = acc[mi][ni][reg];
      }
  }
}

// K_red: out[(t*8+b)*256+d] = sum_hpg part[hpg][(b*1024+t)*256+d] + bo[d]
__global__ __launch_bounds__(256) void k_red(const float* __restrict__ part,
                                             const float* __restrict__ bo,
                                             float* __restrict__ out)
{
  int i = blockIdx.x * 256 + threadIdx.x;   // over 8192*64 float4s
  int m = i >> 6, d4 = i & 63;
  float4 s = ((const float4*)part)[i];
#pragma unroll
  for (int hp = 1; hp < 4; ++hp) {
    float4 p = ((const float4*)(part + (size_t)hp * BT * 256))[i];
    s.x += p.x; s.y += p.y; s.z += p.z; s.w += p.w;
  }
  float4 b4 = ((const float4*)bo)[d4];
  s.x += b4.x; s.y += b4.y; s.z += b4.z; s.w += b4.w;
  int t = m & 1023, b = m >> 10;
  ((float4*)out)[(t * 8 + b) * 64 + d4] = s;
}

// ---------------------------------------------------------------------------
extern "C" void kernel_launch(void* const* d_in, const int* in_sizes, int n_in,
                              void* d_out, int out_size, void* d_ws, size_t ws_size,
                              hipStream_t stream)
{
  const float* Q  = (const float*)d_in[0];
  const float* Wq = (const float*)d_in[1];
  const float* bq = (const float*)d_in[2];
  const float* Wk = (const float*)d_in[3];
  const float* bk = (const float*)d_in[4];
  const float* Wv = (const float*)d_in[5];
  const float* bv = (const float*)d_in[6];
  const float* Wo = (const float*)d_in[7];
  const float* bo = (const float*)d_in[8];
  float* out = (float*)d_out;

  // ---- sizes ----
  const size_t QB_B  = (size_t)BT * DIN * 2;           //  4 MiB
  const size_t W_B   = (size_t)NH * EH * DIN * 2;      //  2 MiB each
  const size_t WT_B  = 3 * W_B;                        //  6 MiB
  const size_t GM_B  = (size_t)NH * 65536 * 2;         //  1 MiB each (GT, Mh)
  const size_t VEC_B = (size_t)NH * 256 * 4;           //  8 KiB each (u,w,wb)
  const size_t RT_B  = (size_t)NH * BT * 4;            // 256 KiB each (rt,ct)
  const size_t CP_B  = (size_t)64 * 4 * T_SEQ * 4;     //  1 MiB (colpart)
  const size_t QG_B  = (size_t)NH * BT * 256 * 2;      // 32 MiB
  const size_t VW_B  = (size_t)NH * 256 * BT * 2;      // 32 MiB
  const size_t PART_B= (size_t)4 * BT * 256 * 4;       // 32 MiB (4 head-pairs)
  const size_t P1    = (size_t)T_SEQ * T_SEQ * 2;      //  2 MiB per z

  const size_t fixedB = QB_B + 4 * W_B + WT_B + 2 * GM_B + 3 * VEC_B + 64
                      + 2 * RT_B + CP_B + QG_B + VW_B + PART_B + 16384;

  int HG = 8;
  while (HG > 2 && fixedB + (size_t)HG * 8 * P1 > ws_size) HG >>= 1;

  char* w = (char*)d_ws;
  auto alloc = [&](size_t bytes) {
    char* p = w;
    w += (bytes + 255) & ~(size_t)255;
    return p;
  };
  short* Qb   = (short*)alloc(QB_B);     // cvt arena start (contiguous)
  short* Wqb  = (short*)alloc(W_B);
  short* Wkb  = (short*)alloc(W_B);  (void)Wkb;
  short* Wvb  = (short*)alloc(W_B);  (void)Wvb;
  short* Wob  = (short*)alloc(W_B);
  short* WT   = (short*)alloc(WT_B);
  short* GT   = (short*)alloc(GM_B);
  short* Mh   = (short*)alloc(GM_B);
  float* uA   = (float*)alloc(VEC_B);
  float* wA   = (float*)alloc(VEC_B);
  float* wbA  = (float*)alloc(VEC_B);
  float* c0A  = (float*)alloc(64);
  float* rt   = (float*)alloc(RT_B);
  float* ct   = (float*)alloc(RT_B);
  float* cpart= (float*)alloc(CP_B);
  short* qg   = (short*)alloc(QG_B);
  short* vwgT = (short*)alloc(VW_B);
  float* part = (float*)alloc(PART_B);
  short* Pbuf = (short*)alloc((size_t)HG * 8 * P1);

  // ---- pipeline ----
  k_cvt_all<<<dim3(2048), 256, 0, stream>>>(Q, Wq, Wk, Wv, Wo, Qb);
  k_wtr <<<dim3(4, 8, 24), 256, 0, stream>>>(Wqb, WT);
  k_prep<<<dim3(32), 512, 0, stream>>>(WT, Wob, GT, Mh);
  k_vec <<<dim3(25), 256, 0, stream>>>(WT, Wob, bq, bk, bv, uA, wA, wbA, c0A);
  k_qg  <<<dim3(32, 2, 8), 512, 0, stream>>>(Qb, GT, qg);
  k_vwg <<<dim3(64, 8), 512, 0, stream>>>(Qb, Mh, wbA, vwgT);
  k_rc  <<<dim3(32), 256, 0, stream>>>(Qb, uA, wA, rt, ct);

  for (int h0 = 0; h0 < NH; h0 += HG) {
    k_pgen  <<<dim3(4, 8, HG * 8), 512, 0, stream>>>(qg, Qb, rt, ct, c0A,
                                                     Pbuf, cpart, h0, HG);
    k_scalev<<<dim3(4, HG * 8), 256, 0, stream>>>(vwgT, cpart, h0, HG);
    k_ogemm <<<dim3(4, 2, (HG / 2) * 8), 512, 0, stream>>>(Pbuf, vwgT, part, h0, HG);
  }
  k_red<<<dim3(BT * 256 / 4 / 256), 256, 0, stream>>>(part, bo, out);
}

// Round 16
// 239.428 us; speedup vs baseline: 1.0488x; 1.0488x over previous
//
#include <hip/hip_runtime.h>
#include <stdint.h>
#include <stddef.h>

// Problem constants (MultiHeadAttention_52759378264454)
constexpr int T_SEQ = 1024;
constexpr int BATCH = 8;
constexpr int DIN   = 256;
constexpr int NH    = 8;
constexpr int EH    = 512;
constexpr int HE    = NH * EH;        // 4096
constexpr int BT    = BATCH * T_SEQ;  // 8192
constexpr float SCALE = 0.044194173824159216f; // 1/sqrt(512)
constexpr float C2   = 0.06375814170236324f;   // SCALE * log2(e)

typedef __attribute__((ext_vector_type(8)))  short s16x8;
typedef __attribute__((ext_vector_type(4)))  short s16x4;
typedef __attribute__((ext_vector_type(16))) float f32x16;

__device__ __forceinline__ short f2bf(float f) {
  union { float f; uint32_t u; } c; c.f = f;
  uint32_t u = c.u;
  u += 0x7fffu + ((u >> 16) & 1u);   // RNE
  return (short)(u >> 16);
}
__device__ __forceinline__ float bf2f(short s) {
  union { uint32_t u; float f; } c; c.u = ((uint32_t)(uint16_t)s) << 16;
  return c.f;
}

// async global->LDS, 16B/lane. LDS dest = wave-uniform base + lane*16 (HW).
__device__ __forceinline__ void gload16(const short* g, short* l) {
  __builtin_amdgcn_global_load_lds(
      (__attribute__((address_space(1))) void*)(void*)const_cast<short*>(g),
      (__attribute__((address_space(3))) void*)(void*)l, 16, 0, 0);
}

#define WAITVM(N) asm volatile("s_waitcnt vmcnt(" #N ")" ::: "memory")
#define BARF do { asm volatile("" ::: "memory"); __builtin_amdgcn_s_barrier(); \
                  asm volatile("" ::: "memory"); } while (0)

// ---------------------------------------------------------------------------
// r5 core (best measured): 8-wave 256x128 GEMM, BK=32, mfma_f32_32x32x16_bf16,
// double-buffered 48 KiB LDS, counted vmcnt(3) (tile t+2 in flight).
// C[256,128] += A[256,K]*B[128,K]^T, K-major bf16. Waves 4wm x 2wn, 64x64 ea.
// Trailing barrier at loop end (safe to reuse LDS / call again).
// ---------------------------------------------------------------------------
template<int NT>   // K = NT*32, NT >= 2
__device__ __forceinline__ void gemm32(const short* __restrict__ Ag, int lda,
                                       const short* __restrict__ Bg, int ldb,
                                       short* lds, f32x16 (&acc)[2][2])
{
  const int tid = threadIdx.x;
  const int l   = tid & 63, wv = tid >> 6;
  const int hi  = l >> 5;
  const int Rw  = (wv >> 1) * 64, Cw = (wv & 1) * 64;
  const int fl  = (l & 3) ^ ((l >> 2) & 3);

  int oA[2][2], oB[2][2];
#pragma unroll
  for (int kk = 0; kk < 2; ++kk) {
    int cp = (((kk << 1) | hi) ^ fl) * 8;
#pragma unroll
    for (int mi = 0; mi < 2; ++mi) oA[kk][mi] = (Rw + mi * 32 + (l & 31)) * 32 + cp;
#pragma unroll
    for (int ni = 0; ni < 2; ++ni) oB[kk][ni] = 8192 + (Cw + ni * 32 + (l & 31)) * 32 + cp;
  }

  const int rA0 = tid >> 2;
  const int sA0 = ((tid & 3) ^ ((rA0 & 3) ^ ((rA0 >> 2) & 3))) * 8;
  const int cA1 = tid + 512, rA1 = cA1 >> 2;
  const int sA1 = ((cA1 & 3) ^ ((rA1 & 3) ^ ((rA1 >> 2) & 3))) * 8;
  const int dA0 = (wv * 64) * 8, dA1 = (wv * 64 + 512) * 8, dB0 = 8192 + (wv * 64) * 8;

  auto stage = [&](int t) {
    short* slot = lds + (t & 1) * 12288;
    const int ko = t * 32;
    gload16(Ag + (size_t)rA0 * lda + ko + sA0, slot + dA0);
    gload16(Ag + (size_t)rA1 * lda + ko + sA1, slot + dA1);
    gload16(Bg + (size_t)rA0 * ldb + ko + sA0, slot + dB0);
  };

  stage(0); stage(1);

#pragma unroll 1
  for (int t = 0; t < NT; ++t) {
    const short* buf = lds + (t & 1) * 12288;
    if (t == NT - 1) { WAITVM(0); } else { WAITVM(3); }
    BARF;
#pragma unroll
    for (int kk = 0; kk < 2; ++kk) {
      s16x8 a0 = *(const s16x8*)(buf + oA[kk][0]);
      s16x8 a1 = *(const s16x8*)(buf + oA[kk][1]);
      s16x8 b0 = *(const s16x8*)(buf + oB[kk][0]);
      s16x8 b1 = *(const s16x8*)(buf + oB[kk][1]);
      __builtin_amdgcn_s_setprio(1);
      acc[0][0] = __builtin_amdgcn_mfma_f32_32x32x16_bf16(a0, b0, acc[0][0], 0, 0, 0);
      acc[0][1] = __builtin_amdgcn_mfma_f32_32x32x16_bf16(a0, b1, acc[0][1], 0, 0, 0);
      acc[1][0] = __builtin_amdgcn_mfma_f32_32x32x16_bf16(a1, b0, acc[1][0], 0, 0, 0);
      acc[1][1] = __builtin_amdgcn_mfma_f32_32x32x16_bf16(a1, b1, acc[1][1], 0, 0, 0);
      __builtin_amdgcn_s_setprio(0);
    }
    BARF;
    if (t + 2 < NT) stage(t + 2);
  }
}

#define CROW(mi, reg) ((wv >> 1) * 64 + (mi) * 32 + ((reg) & 3) + 8 * ((reg) >> 2) + 4 * hi)
#define CCOL(ni)      ((wv & 1) * 64 + (ni) * 32 + (l & 31))

// ---------------------------------------------------------------------------
// K0: fused fp32->bf16 cast; Qb transposed to [b][t][d]; weights copied.
// ---------------------------------------------------------------------------
__global__ __launch_bounds__(256) void k_cvt_all(
    const float* __restrict__ Q,  const float* __restrict__ Wq,
    const float* __restrict__ Wk, const float* __restrict__ Wv,
    const float* __restrict__ Wo, short* __restrict__ dst)
{
  constexpr int N_Q = 524288;              // 1024*8*256/4
  constexpr int N_W = 262144;              // 8*512*256/4
  constexpr int TOT = N_Q + 4 * N_W;
  int i  = blockIdx.x * 256 + threadIdx.x;
  int st = gridDim.x * 256;
  for (; i < TOT; i += st) {
    const float* s; int off;
    if (i < N_Q) {
      int b = i >> 16, t = (i >> 6) & 1023, d4 = i & 63;
      s = Q; off = (t * 8 + b) * 64 + d4;
    }
    else if (i < N_Q + N_W)     { s = Wq; off = i - N_Q; }
    else if (i < N_Q + 2 * N_W) { s = Wk; off = i - N_Q - N_W; }
    else if (i < N_Q + 3 * N_W) { s = Wv; off = i - N_Q - 2 * N_W; }
    else                        { s = Wo; off = i - N_Q - 3 * N_W; }
    float4 v = ((const float4*)s)[off];
    s16x4 o = { f2bf(v.x), f2bf(v.y), f2bf(v.z), f2bf(v.w) };
    ((s16x4*)dst)[i] = o;
  }
}

// ---------------------------------------------------------------------------
// K_wtr: WT[mat][h][d][e] = W[mat][h][e][d]  (mat 0..2 = Wq,Wk,Wv)
// grid (4 d-tiles, 8 e-tiles, 24 = mat*8+h), 256 thr
// ---------------------------------------------------------------------------
__global__ __launch_bounds__(256) void k_wtr(const short* __restrict__ Wbase,
                                             short* __restrict__ WT)
{
  __shared__ short tl[64][72];
  const int dt = blockIdx.x, et = blockIdx.y, mz = blockIdx.z;
  const int mat = mz >> 3, h = mz & 7;
  const short* src = Wbase + ((size_t)mat * NH + h) * EH * DIN;
  short* dst = WT + ((size_t)mat * NH + h) * DIN * EH;
  const int tid = threadIdx.x;

#pragma unroll
  for (int rep = 0; rep < 2; ++rep) {
    int er = (tid >> 3) + rep * 32;
    int dc = (tid & 7) * 8;
    s16x8 v = *(const s16x8*)&src[(size_t)(et * 64 + er) * DIN + dt * 64 + dc];
#pragma unroll
    for (int j = 0; j < 8; ++j) tl[er][dc + j] = v[j];
  }
  __syncthreads();
#pragma unroll
  for (int rep = 0; rep < 2; ++rep) {
    int dr = (tid >> 3) + rep * 32;
    int ec = (tid & 7) * 8;
    s16x8 o;
#pragma unroll
    for (int j = 0; j < 8; ++j) o[j] = tl[ec + j][dr];
    *(s16x8*)&dst[(size_t)(dt * 64 + dr) * EH + et * 64 + ec] = o;
  }
}

// ---------------------------------------------------------------------------
// K_prep: p=0: GT[h][d2][d1] = sum_e WkT[h][d2,e]*WqT[h][d1,e]  (= Wq^T Wk)
//         p=1: Mh[h][d][dd]  = sum_e Wo[d,h*512+e]*WvT[h][dd,e] (= Wo_h Wv_h)
// grid 32: f -> by(1b), h(3b), p(1b).
// ---------------------------------------------------------------------------
__global__ __launch_bounds__(512) void k_prep(
    const short* __restrict__ WT, const short* __restrict__ Wob,
    short* __restrict__ GT, short* __restrict__ Mh)
{
  __shared__ short lds[24576];
  const int f = blockIdx.x;
  const int by = f & 1, h = (f >> 1) & 7, p = f >> 4;

  const short* WqT = WT + (size_t)0 * NH * DIN * EH + (size_t)h * DIN * EH;
  const short* WkT = WT + (size_t)1 * NH * DIN * EH + (size_t)h * DIN * EH;
  const short* WvT = WT + (size_t)2 * NH * DIN * EH + (size_t)h * DIN * EH;

  const short* Ag; int lda; const short* Bg; int ldb; short* Cg;
  if (p == 0) { Ag = WkT; lda = EH; Bg = WqT + (size_t)by * 128 * EH; ldb = EH;
                Cg = GT + (size_t)h * 65536; }
  else        { Ag = Wob + (size_t)h * EH; lda = HE;
                Bg = WvT + (size_t)by * 128 * EH; ldb = EH;
                Cg = Mh + (size_t)h * 65536; }

  f32x16 acc[2][2] = {};
  gemm32<EH / 32>(Ag, lda, Bg, ldb, lds, acc);

  const int l = threadIdx.x & 63, wv = threadIdx.x >> 6, hi = l >> 5;
#pragma unroll
  for (int ni = 0; ni < 2; ++ni) {
    int col = by * 128 + CCOL(ni);
#pragma unroll
    for (int mi = 0; mi < 2; ++mi)
#pragma unroll
      for (int reg = 0; reg < 16; ++reg)
        Cg[(size_t)CROW(mi, reg) * 256 + col] = f2bf(acc[mi][ni][reg]);
  }
}

// ---------------------------------------------------------------------------
// K_vec (parallel): grid 25 x 256 thr. blocks 0..23: (mat, h), thread = d.
// block 24: c0[h] = sum_e bq*bk.
// ---------------------------------------------------------------------------
__global__ __launch_bounds__(256) void k_vec(
    const short* __restrict__ WT, const short* __restrict__ Wob,
    const float* __restrict__ bq, const float* __restrict__ bk,
    const float* __restrict__ bv,
    float* __restrict__ uA, float* __restrict__ wA,
    float* __restrict__ wbA, float* __restrict__ c0A)
{
  const int f = blockIdx.x;
  const int d = threadIdx.x;
  if (f < 24) {
    const int mat = f >> 3, h = f & 7;
    __shared__ float bL[512];
    const float* bias = (mat == 0 ? bk : mat == 1 ? bq : bv) + h * EH;
    bL[d] = bias[d];
    bL[d + 256] = bias[d + 256];
    __syncthreads();
    const short* row;
    if (mat == 0)      row = WT + ((size_t)h * DIN + d) * EH;               // WqT
    else if (mat == 1) row = WT + ((size_t)(NH + h) * DIN + d) * EH;        // WkT
    else               row = Wob + (size_t)d * HE + h * EH;                 // Wo
    float acc = 0.f;
#pragma unroll 4
    for (int e8 = 0; e8 < EH; e8 += 8) {
      s16x8 v = *(const s16x8*)(row + e8);
#pragma unroll
      for (int j = 0; j < 8; ++j) acc += bf2f(v[j]) * bL[e8 + j];
    }
    float* out = (mat == 0 ? uA : mat == 1 ? wA : wbA);
    out[h * 256 + d] = acc;
  } else {
    const int h = d >> 5, i = d & 31;
    float c = 0.f;
#pragma unroll
    for (int j = 0; j < 16; ++j) {
      int e = i * 16 + j;
      c += bq[h * EH + e] * bk[h * EH + e];
    }
    c += __shfl_xor(c, 1);  c += __shfl_xor(c, 2);
    c += __shfl_xor(c, 4);  c += __shfl_xor(c, 8);
    c += __shfl_xor(c, 16);
    if (i == 0) c0A[h] = c;
  }
}

// ---------------------------------------------------------------------------
// K_qg: qg[h][m][d2] = sum_d1 Qb[m,d1]*GT[h][d2,d1].  grid (32,2,8). NT=8.
// ---------------------------------------------------------------------------
__global__ __launch_bounds__(512) void k_qg(
    const short* __restrict__ Qb, const short* __restrict__ GT,
    short* __restrict__ qg)
{
  __shared__ short lds[24576];
  const int bx = blockIdx.x, by = blockIdx.y, h = blockIdx.z;
  const short* Ag = Qb + (size_t)bx * 256 * DIN;
  const short* Bg = GT + (size_t)h * 65536 + (size_t)by * 128 * 256;

  f32x16 acc[2][2] = {};
  gemm32<DIN / 32>(Ag, DIN, Bg, 256, lds, acc);

  short* outp = qg + (size_t)h * BT * 256;
  const int l = threadIdx.x & 63, wv = threadIdx.x >> 6, hi = l >> 5;
#pragma unroll
  for (int ni = 0; ni < 2; ++ni) {
    int col = by * 128 + CCOL(ni);
#pragma unroll
    for (int mi = 0; mi < 2; ++mi)
#pragma unroll
      for (int reg = 0; reg < 16; ++reg)
        outp[(size_t)(bx * 256 + CROW(mi, reg)) * 256 + col] = f2bf(acc[mi][ni][reg]);
  }
}

// ---------------------------------------------------------------------------
// K_vwg: vwgT[h][d][m] = sum_dd Mh[h][d,dd]*Qb[m,dd] + wb[h][d].
// grid (64 by, 8 h). NT=8.
// ---------------------------------------------------------------------------
__global__ __launch_bounds__(512) void k_vwg(
    const short* __restrict__ Qb, const short* __restrict__ Mh,
    const float* __restrict__ wbA, short* __restrict__ vwgT)
{
  __shared__ short lds[24576];
  const int by = blockIdx.x, h = blockIdx.y;
  const short* Ag = Mh + (size_t)h * 65536;
  const short* Bg = Qb + (size_t)by * 128 * DIN;

  f32x16 acc[2][2] = {};
  gemm32<DIN / 32>(Ag, 256, Bg, DIN, lds, acc);

  short* outp = vwgT + (size_t)h * 256 * BT;
  const int l = threadIdx.x & 63, wv = threadIdx.x >> 6, hi = l >> 5;
#pragma unroll
  for (int mi = 0; mi < 2; ++mi)
#pragma unroll
    for (int reg = 0; reg < 16; ++reg) {
      int d = CROW(mi, reg);
      float bia = wbA[h * 256 + d];
#pragma unroll
      for (int ni = 0; ni < 2; ++ni)
        outp[(size_t)d * BT + by * 128 + CCOL(ni)] = f2bf(acc[mi][ni][reg] + bia);
    }
}

// ---------------------------------------------------------------------------
// K_rc: rt[h][m] = sum_d Qb[m,d]*u[h][d]; ct[h][m] = sum_d Qb[m,d]*w[h][d]
// grid (32), 256 thr.
// ---------------------------------------------------------------------------
__global__ __launch_bounds__(256) void k_rc(
    const short* __restrict__ Qb, const float* __restrict__ uA,
    const float* __restrict__ wA, float* __restrict__ rt, float* __restrict__ ct)
{
  __shared__ float uL[2048], wL[2048];
  const int tid = threadIdx.x;
  for (int i = tid; i < 2048; i += 256) { uL[i] = uA[i]; wL[i] = wA[i]; }
  __syncthreads();
  int m = blockIdx.x * 256 + tid;
  float r[8] = {}, c[8] = {};
  const short* row = Qb + (size_t)m * DIN;
  for (int ch = 0; ch < 32; ++ch) {
    s16x8 v = *(const s16x8*)(row + ch * 8);
#pragma unroll
    for (int j = 0; j < 8; ++j) {
      float q = bf2f(v[j]);
      int d = ch * 8 + j;
#pragma unroll
      for (int h = 0; h < 8; ++h) {
        r[h] += q * uL[h * 256 + d];
        c[h] += q * wL[h * 256 + d];
      }
    }
  }
#pragma unroll
  for (int h = 0; h < 8; ++h) {
    rt[(size_t)h * BT + m] = r[h];
    ct[(size_t)h * BT + m] = c[h];
  }
}

// ---------------------------------------------------------------------------
// K_pgen: P[zz][t][s] = exp2(C2*(qk) + rtL[t] + ctL[s]) + col partials
// grid (4,8,HG*8). L2-locality decode: zz fixed per XCD, varies SLOWEST
// (zi = rest>>5) so the per-XCD working set is one z (~2.5 MB <= 4 MB L2).
// ---------------------------------------------------------------------------
__global__ __launch_bounds__(512) void k_pgen(
    const short* __restrict__ qg, const short* __restrict__ Qb,
    const float* __restrict__ rt, const float* __restrict__ ct,
    const float* __restrict__ c0A,
    short* __restrict__ Pbuf, float* __restrict__ colpart, int h0, int HG)
{
  __shared__ short lds[24576];
  __shared__ float rtL[256], ctL[128];
  int f = blockIdx.x + (blockIdx.y << 2) + (blockIdx.z << 5);
  int xcd = f & 7, rest = f >> 3;               // rest in [0, 32*HG)
  int zi = rest >> 5, rb = rest & 31;           // zi SLOWEST: one z at a time
  int zz = xcd * HG + zi;                       // [0, HG*8)
  int bx = rb & 3, by = rb >> 2;
  const int zg = h0 * 8 + zz;                   // global z
  const int h = zg >> 3, b = zg & 7;

  const short* Ag = qg + ((size_t)h * BT + b * 1024 + bx * 256) * 256;
  const short* Bg = Qb + (size_t)(b * 1024 + by * 128) * 256;

  f32x16 acc[2][2] = {};
  gemm32<DIN / 32>(Ag, 256, Bg, 256, lds, acc);

  const int tid = threadIdx.x;
  const float c0h = c0A[h];
  if (tid < 256)
    rtL[tid] = C2 * rt[(size_t)h * BT + b * 1024 + bx * 256 + tid];
  else if (tid < 384)
    ctL[tid - 256] = C2 * (ct[(size_t)h * BT + b * 1024 + by * 128 + (tid - 256)] + c0h);
  __syncthreads();

  short* Pb = Pbuf + (size_t)zz * T_SEQ * T_SEQ;
  const int l = tid & 63, wv = tid >> 6, hi = l >> 5;

  float cs[2] = {0.f, 0.f};
#pragma unroll
  for (int ni = 0; ni < 2; ++ni) {
    int scol = CCOL(ni);
    float ctv = ctL[scol];
#pragma unroll
    for (int mi = 0; mi < 2; ++mi)
#pragma unroll
      for (int reg = 0; reg < 16; ++reg) {
        int trow = CROW(mi, reg);
        float ev = exp2f(fmaf(acc[mi][ni][reg], C2, rtL[trow] + ctv));
        cs[ni] += ev;
        Pb[(size_t)(bx * 256 + trow) * T_SEQ + by * 128 + scol] = f2bf(ev);
      }
  }
  cs[0] += __shfl_xor(cs[0], 32);
  cs[1] += __shfl_xor(cs[1], 32);
  __syncthreads();
  float* csL = (float*)lds;
  if (l < 32) {
#pragma unroll
    for (int ni = 0; ni < 2; ++ni) csL[(wv >> 1) * 128 + CCOL(ni)] = cs[ni];
  }
  __syncthreads();
  if (tid < 128) {
    float tot = csL[tid] + csL[128 + tid] + csL[256 + tid] + csL[384 + tid];
    colpart[((size_t)zg * 4 + bx) * T_SEQ + by * 128 + tid] = tot;
  }
}

// ---------------------------------------------------------------------------
// K_scalev: vwgT[h][d][b*T+t] *= 1/sum_p colpart[(zg*4+p)][t]
// grid (4 et, HG*8 zz)
// ---------------------------------------------------------------------------
__global__ __launch_bounds__(256) void k_scalev(
    short* __restrict__ vwgT, const float* __restrict__ colpart, int h0, int HG)
{
  __shared__ float invL[1024];
  const int et = blockIdx.x, zz = blockIdx.y;
  const int zg = h0 * 8 + zz;
  const int h = zg >> 3, b = zg & 7;
  const int tid = threadIdx.x;

#pragma unroll
  for (int it = 0; it < 4; ++it) {
    int t = it * 256 + tid;
    float s = 0.f;
#pragma unroll
    for (int p = 0; p < 4; ++p) s += colpart[((size_t)zg * 4 + p) * T_SEQ + t];
    invL[t] = 1.0f / s;
  }
  __syncthreads();

  short* base = vwgT + (size_t)h * 256 * BT + (size_t)et * 64 * BT + (size_t)b * 1024;
  for (int c = tid; c < 64 * 128; c += 256) {
    int row = c >> 7, col = (c & 127) * 8;
    short* p = &base[(size_t)row * BT + col];
    s16x8 v = *(s16x8*)p;
#pragma unroll
    for (int j = 0; j < 8; ++j) v[j] = f2bf(bf2f(v[j]) * invL[col + j]);
    *(s16x8*)p = v;
  }
}

// ---------------------------------------------------------------------------
// K_ogemm (2-head accumulation): for head-pair hp, batch b:
// part[hpg][b*T+t][d] = sum_{h in pair} sum_s P[zz(h,b)][t,s]*vwgT[h][d][b*T+s]
// grid (4 bx, 2 by, (HG/2)*8). L2-locality decode: zp fixed per XCD (both
// by-partners + all bx of a zp co-XCD -> P fetched once from HBM).
// ---------------------------------------------------------------------------
__global__ __launch_bounds__(512) void k_ogemm(
    const short* __restrict__ Pbuf, const short* __restrict__ vwgT,
    float* __restrict__ part, int h0, int HG)
{
  __shared__ short lds[24576];
  const int NP = (HG / 2) * 8;                  // total zp values
  const int PPX = NP / 8 == 0 ? 1 : NP / 8;     // zp per XCD
  int f = blockIdx.x + (blockIdx.y << 2) + blockIdx.z * 8;
  int xcd = f & 7, rest = f >> 3;               // rest in [0, 8*PPX)
  int pi = rest >> 3, rb = rest & 7;            // zp SLOWEST within an XCD
  int zp = xcd * PPX + pi;                      // [0, NP): b*(HG/2)+hp
  int bx = rb & 3, by = rb >> 2;
  const int b  = zp / (HG / 2);
  const int hp = zp % (HG / 2);
  const int hA = h0 + 2 * hp, hB = hA + 1;
  const int hpg = hA >> 1;                      // global pair index [0,4)

  f32x16 acc[2][2] = {};
#pragma unroll
  for (int u = 0; u < 2; ++u) {
    const int h = u == 0 ? hA : hB;
    const int zz = (h - h0) * 8 + b;            // Pbuf slot
    const short* Ag = Pbuf + (size_t)zz * T_SEQ * T_SEQ + (size_t)bx * 256 * T_SEQ;
    const short* Bg = vwgT + (size_t)h * 256 * BT + (size_t)by * 128 * BT + (size_t)b * 1024;
    gemm32<T_SEQ / 32>(Ag, T_SEQ, Bg, BT, lds, acc);
  }

  float* pp = part + (size_t)hpg * BT * 256;
  const int l = threadIdx.x & 63, wv = threadIdx.x >> 6, hi = l >> 5;
#pragma unroll
  for (int ni = 0; ni < 2; ++ni) {
    int d = by * 128 + CCOL(ni);
#pragma unroll
    for (int mi = 0; mi < 2; ++mi)
#pragma unroll
      for (int reg = 0; reg < 16; ++reg) {
        int m = b * 1024 + bx * 256 + CROW(mi, reg);
        pp[(size_t)m * 256 + d] = acc[mi][ni][reg];
      }
  }
}

// K_red: out[(t*8+b)*256+d] = sum_hpg part[hpg][(b*1024+t)*256+d] + bo[d]
__global__ __launch_bounds__(256) void k_red(const float* __restrict__ part,
                                             const float* __restrict__ bo,
                                             float* __restrict__ out)
{
  int i = blockIdx.x * 256 + threadIdx.x;   // over 8192*64 float4s
  int m = i >> 6, d4 = i & 63;
  float4 s = ((const float4*)part)[i];
#pragma unroll
  for (int hp = 1; hp < 4; ++hp) {
    float4 p = ((const float4*)(part + (size_t)hp * BT * 256))[i];
    s.x += p.x; s.y += p.y; s.z += p.z; s.w += p.w;
  }
  float4 b4 = ((const float4*)bo)[d4];
  s.x += b4.x; s.y += b4.y; s.z += b4.z; s.w += b4.w;
  int t = m & 1023, b = m >> 10;
  ((float4*)out)[(t * 8 + b) * 64 + d4] = s;
}

// ---------------------------------------------------------------------------
extern "C" void kernel_launch(void* const* d_in, const int* in_sizes, int n_in,
                              void* d_out, int out_size, void* d_ws, size_t ws_size,
                              hipStream_t stream)
{
  const float* Q  = (const float*)d_in[0];
  const float* Wq = (const float*)d_in[1];
  const float* bq = (const float*)d_in[2];
  const float* Wk = (const float*)d_in[3];
  const float* bk = (const float*)d_in[4];
  const float* Wv = (const float*)d_in[5];
  const float* bv = (const float*)d_in[6];
  const float* Wo = (const float*)d_in[7];
  const float* bo = (const float*)d_in[8];
  float* out = (float*)d_out;

  // ---- sizes ----
  const size_t QB_B  = (size_t)BT * DIN * 2;           //  4 MiB
  const size_t W_B   = (size_t)NH * EH * DIN * 2;      //  2 MiB each
  const size_t WT_B  = 3 * W_B;                        //  6 MiB
  const size_t GM_B  = (size_t)NH * 65536 * 2;         //  1 MiB each (GT, Mh)
  const size_t VEC_B = (size_t)NH * 256 * 4;           //  8 KiB each (u,w,wb)
  const size_t RT_B  = (size_t)NH * BT * 4;            // 256 KiB each (rt,ct)
  const size_t CP_B  = (size_t)64 * 4 * T_SEQ * 4;     //  1 MiB (colpart)
  const size_t QG_B  = (size_t)NH * BT * 256 * 2;      // 32 MiB
  const size_t VW_B  = (size_t)NH * 256 * BT * 2;      // 32 MiB
  const size_t PART_B= (size_t)4 * BT * 256 * 4;       // 32 MiB (4 head-pairs)
  const size_t P1    = (size_t)T_SEQ * T_SEQ * 2;      //  2 MiB per z

  const size_t fixedB = QB_B + 4 * W_B + WT_B + 2 * GM_B + 3 * VEC_B + 64
                      + 2 * RT_B + CP_B + QG_B + VW_B + PART_B + 16384;

  int HG = 8;
  while (HG > 2 && fixedB + (size_t)HG * 8 * P1 > ws_size) HG >>= 1;

  char* w = (char*)d_ws;
  auto alloc = [&](size_t bytes) {
    char* p = w;
    w += (bytes + 255) & ~(size_t)255;
    return p;
  };
  short* Qb   = (short*)alloc(QB_B);     // cvt arena start (contiguous)
  short* Wqb  = (short*)alloc(W_B);
  short* Wkb  = (short*)alloc(W_B);  (void)Wkb;
  short* Wvb  = (short*)alloc(W_B);  (void)Wvb;
  short* Wob  = (short*)alloc(W_B);
  short* WT   = (short*)alloc(WT_B);
  short* GT   = (short*)alloc(GM_B);
  short* Mh   = (short*)alloc(GM_B);
  float* uA   = (float*)alloc(VEC_B);
  float* wA   = (float*)alloc(VEC_B);
  float* wbA  = (float*)alloc(VEC_B);
  float* c0A  = (float*)alloc(64);
  float* rt   = (float*)alloc(RT_B);
  float* ct   = (float*)alloc(RT_B);
  float* cpart= (float*)alloc(CP_B);
  short* qg   = (short*)alloc(QG_B);
  short* vwgT = (short*)alloc(VW_B);
  float* part = (float*)alloc(PART_B);
  short* Pbuf = (short*)alloc((size_t)HG * 8 * P1);

  // ---- pipeline ----
  k_cvt_all<<<dim3(2048), 256, 0, stream>>>(Q, Wq, Wk, Wv, Wo, Qb);
  k_wtr <<<dim3(4, 8, 24), 256, 0, stream>>>(Wqb, WT);
  k_prep<<<dim3(32), 512, 0, stream>>>(WT, Wob, GT, Mh);
  k_vec <<<dim3(25), 256, 0, stream>>>(WT, Wob, bq, bk, bv, uA, wA, wbA, c0A);
  k_qg  <<<dim3(32, 2, 8), 512, 0, stream>>>(Qb, GT, qg);
  k_vwg <<<dim3(64, 8), 512, 0, stream>>>(Qb, Mh, wbA, vwgT);
  k_rc  <<<dim3(32), 256, 0, stream>>>(Qb, uA, wA, rt, ct);

  for (int h0 = 0; h0 < NH; h0 += HG) {
    k_pgen  <<<dim3(4, 8, HG * 8), 512, 0, stream>>>(qg, Qb, rt, ct, c0A,
                                                     Pbuf, cpart, h0, HG);
    k_scalev<<<dim3(4, HG * 8), 256, 0, stream>>>(vwgT, cpart, h0, HG);
    k_ogemm <<<dim3(4, 2, (HG / 2) * 8), 512, 0, stream>>>(Pbuf, vwgT, part, h0, HG);
  }
  k_red<<<dim3(BT * 256 / 4 / 256), 256, 0, stream>>>(part, bo, out);
}